// Round 1
// baseline (393.592 us; speedup 1.0000x reference)
//
#include <hip/hip_runtime.h>
#include <hip/hip_bf16.h>

typedef unsigned short u16;
typedef __bf16 bf16x8 __attribute__((ext_vector_type(8)));
typedef float f32x4 __attribute__((ext_vector_type(4)));

#define N_ROWS 8192
#define M_ROWS 4096
#define E_DIM  512

// ---------- helpers ----------
__device__ __forceinline__ u16 f2bf(float f) {
    unsigned u = __float_as_uint(f);
    u += 0x7FFF + ((u >> 16) & 1);   // RNE
    return (u16)(u >> 16);
}
__device__ __forceinline__ float bf2f(u16 u) {
    return __uint_as_float(((unsigned)u) << 16);
}

// ---------- cast fp32 -> bf16, 4 elems/thread ----------
__global__ __launch_bounds__(256)
void cast_bf(const float* __restrict__ in, u16* __restrict__ out, int n4) {
    int i = blockIdx.x * 256 + threadIdx.x;
    if (i < n4) {
        float4 f = reinterpret_cast<const float4*>(in)[i];
        ushort4 o;
        o.x = f2bf(f.x); o.y = f2bf(f.y); o.z = f2bf(f.z); o.w = f2bf(f.w);
        reinterpret_cast<ushort4*>(out)[i] = o;
    }
}

// ---------- GEMM: C[i][j] = sum_k A[i][k]*B[j][k], A,B bf16 K-contiguous ----------
// OUT: 0 = fp32 C[row*ldc+col], 1 = bf16 C[row*ldc+col], 2 = bf16 transposed C[col*ldc+row]
template <int OUT>
__global__ __launch_bounds__(256)
void gemm_bt(const u16* __restrict__ A, int lda,
             const u16* __restrict__ B, int ldb,
             void* __restrict__ Cout, int ldc, int K) {
    __shared__ u16 sA[64 * 40];   // rows padded to 40 bf16 (80B) -> 2-way bank aliasing only
    __shared__ u16 sB[64 * 40];
    const int tid  = threadIdx.x;
    const int col0 = blockIdx.x * 64;
    const int row0 = blockIdx.y * 64;
    const int wave = tid >> 6, lane = tid & 63;
    const int quad = lane >> 4, m16 = lane & 15;
    const int lrow = tid >> 2, lcol = (tid & 3) * 8;

    const u16* aptr = A + (size_t)(row0 + lrow) * lda + lcol;
    const u16* bptr = B + (size_t)(col0 + lrow) * ldb + lcol;

    f32x4 acc[4];
#pragma unroll
    for (int j = 0; j < 4; ++j) acc[j] = (f32x4){0.f, 0.f, 0.f, 0.f};

    for (int k0 = 0; k0 < K; k0 += 32) {
        bf16x8 av = *reinterpret_cast<const bf16x8*>(aptr + k0);
        bf16x8 bv = *reinterpret_cast<const bf16x8*>(bptr + k0);
        __syncthreads();
        *reinterpret_cast<bf16x8*>(&sA[lrow * 40 + lcol]) = av;
        *reinterpret_cast<bf16x8*>(&sB[lrow * 40 + lcol]) = bv;
        __syncthreads();
        bf16x8 af = *reinterpret_cast<const bf16x8*>(&sA[(wave * 16 + m16) * 40 + quad * 8]);
#pragma unroll
        for (int j = 0; j < 4; ++j) {
            bf16x8 bfr = *reinterpret_cast<const bf16x8*>(&sB[(j * 16 + m16) * 40 + quad * 8]);
            acc[j] = __builtin_amdgcn_mfma_f32_16x16x32_bf16(af, bfr, acc[j], 0, 0, 0);
        }
    }

#pragma unroll
    for (int j = 0; j < 4; ++j) {
        const int gcol = col0 + j * 16 + m16;
#pragma unroll
        for (int r = 0; r < 4; ++r) {
            const int grow = row0 + wave * 16 + quad * 4 + r;
            const float v = acc[j][r];
            if constexpr (OUT == 0) {
                reinterpret_cast<float*>(Cout)[(size_t)grow * ldc + gcol] = v;
            } else if constexpr (OUT == 1) {
                reinterpret_cast<u16*>(Cout)[(size_t)grow * ldc + gcol] = f2bf(v);
            } else {
                reinterpret_cast<u16*>(Cout)[(size_t)gcol * ldc + grow] = f2bf(v);
            }
        }
    }
}

// ---------- self attention score: dot(q[n], k[n]) ----------
__global__ __launch_bounds__(256)
void self_dot(const u16* __restrict__ q, const u16* __restrict__ k,
              float* __restrict__ selfS) {
    const int wave = threadIdx.x >> 6, lane = threadIdx.x & 63;
    const int row = blockIdx.x * 4 + wave;
    const uint4 qa = *reinterpret_cast<const uint4*>(q + (size_t)row * E_DIM + lane * 8);
    const uint4 ka = *reinterpret_cast<const uint4*>(k + (size_t)row * E_DIM + lane * 8);
    unsigned qu[4] = {qa.x, qa.y, qa.z, qa.w};
    unsigned ku[4] = {ka.x, ka.y, ka.z, ka.w};
    float s = 0.f;
#pragma unroll
    for (int i = 0; i < 4; ++i) {
        s += bf2f((u16)(qu[i] & 0xFFFF)) * bf2f((u16)(ku[i] & 0xFFFF));
        s += bf2f((u16)(qu[i] >> 16))    * bf2f((u16)(ku[i] >> 16));
    }
#pragma unroll
    for (int off = 32; off; off >>= 1) s += __shfl_down(s, off);
    if (lane == 0) selfS[row] = s;
}

// ---------- row softmax over [self, obs_row]; writes bf16 weights in place ----------
__global__ __launch_bounds__(256)
void softmax_row(float* __restrict__ S, const float* __restrict__ selfS,
                 float* __restrict__ w0) {
    __shared__ float lds[8];
    const int n = blockIdx.x, t = threadIdx.x;
    const int lane = t & 63, wave = t >> 6;
    float* row = S + (size_t)n * M_ROWS;

    float4 v[4];
#pragma unroll
    for (int i = 0; i < 4; ++i) v[i] = reinterpret_cast<const float4*>(row)[i * 256 + t];
    const float s0 = selfS[n];

    float lmax = s0;
#pragma unroll
    for (int i = 0; i < 4; ++i)
        lmax = fmaxf(lmax, fmaxf(fmaxf(v[i].x, v[i].y), fmaxf(v[i].z, v[i].w)));
#pragma unroll
    for (int off = 32; off; off >>= 1) lmax = fmaxf(lmax, __shfl_down(lmax, off));
    if (lane == 0) lds[wave] = lmax;
    __syncthreads();
    const float gmax = fmaxf(fmaxf(lds[0], lds[1]), fmaxf(lds[2], lds[3]));
    __syncthreads();

    const float invT = (float)(1.0 / 22.627416997969522);
    float lsum = 0.f;
#pragma unroll
    for (int i = 0; i < 4; ++i) {
        v[i].x = expf((v[i].x - gmax) * invT); lsum += v[i].x;
        v[i].y = expf((v[i].y - gmax) * invT); lsum += v[i].y;
        v[i].z = expf((v[i].z - gmax) * invT); lsum += v[i].z;
        v[i].w = expf((v[i].w - gmax) * invT); lsum += v[i].w;
    }
#pragma unroll
    for (int off = 32; off; off >>= 1) lsum += __shfl_down(lsum, off);
    if (lane == 0) lds[wave] = lsum;
    __syncthreads();
    const float p0 = expf((s0 - gmax) * invT);
    const float gsum = lds[0] + lds[1] + lds[2] + lds[3] + p0;
    const float inv = 1.f / gsum;

    u16* wrow = reinterpret_cast<u16*>(row);  // bf16 weights alias the row's own bytes
#pragma unroll
    for (int i = 0; i < 4; ++i) {
        ushort4 o;
        o.x = f2bf(v[i].x * inv); o.y = f2bf(v[i].y * inv);
        o.z = f2bf(v[i].z * inv); o.w = f2bf(v[i].w * inv);
        reinterpret_cast<ushort4*>(wrow)[i * 256 + t] = o;
    }
    if (t == 0) w0[n] = p0 * inv;
}

// ---------- epilogue: LN(w0*v_value + O + v_code) ----------
__global__ __launch_bounds__(256)
void final_ln(const float* __restrict__ O, const float* __restrict__ vval,
              const float* __restrict__ w0, const float* __restrict__ vcode,
              const float* __restrict__ gamma, const float* __restrict__ beta,
              float* __restrict__ out) {
    __shared__ float lds[8];
    const int n = blockIdx.x, t = threadIdx.x;
    const int lane = t & 63, wave = t >> 6;
    const size_t base = (size_t)n * E_DIM;
    const float a = w0[n];
    float x0 = fmaf(a, vval[base + t],       O[base + t])       + vcode[base + t];
    float x1 = fmaf(a, vval[base + t + 256], O[base + t + 256]) + vcode[base + t + 256];

    float s = x0 + x1;
#pragma unroll
    for (int off = 32; off; off >>= 1) s += __shfl_down(s, off);
    if (lane == 0) lds[wave] = s;
    __syncthreads();
    const float mu = (lds[0] + lds[1] + lds[2] + lds[3]) * (1.0f / E_DIM);
    __syncthreads();

    const float d0 = x0 - mu, d1 = x1 - mu;
    float vs = d0 * d0 + d1 * d1;
#pragma unroll
    for (int off = 32; off; off >>= 1) vs += __shfl_down(vs, off);
    if (lane == 0) lds[wave] = vs;
    __syncthreads();
    const float var = (lds[0] + lds[1] + lds[2] + lds[3]) * (1.0f / E_DIM);
    const float rs = rsqrtf(var + 1e-6f);

    out[base + t]       = d0 * rs * gamma[t]       + beta[t];
    out[base + t + 256] = d1 * rs * gamma[t + 256] + beta[t + 256];
}

// ---------- workspace layout (bytes, all 256-aligned; total ~182 MiB) ----------
// O (16 MiB) overlays the cast/QBF region, which is dead before the PV GEMM runs.
#define OFF_VCODEBF 0u
#define OFF_OBSBF   8388608u
#define OFF_WQ      12582912u
#define OFF_WK      13107200u
#define OFF_WV      13631488u
#define OFF_QBF     14155776u
#define OFF_KBF     22544384u
#define OFF_VVAL    30932992u
#define OFF_OBSK    47710208u
#define OFF_OBSVT   51904512u
#define OFF_S       56098816u
#define OFF_W0      190316544u
#define OFF_SELF    190349312u
#define OFF_O       0u

extern "C" void kernel_launch(void* const* d_in, const int* in_sizes, int n_in,
                              void* d_out, int out_size, void* d_ws, size_t ws_size,
                              hipStream_t stream) {
    const float* v_code   = (const float*)d_in[0];
    const float* obs_code = (const float*)d_in[1];
    const float* Wq       = (const float*)d_in[2];
    const float* Wk       = (const float*)d_in[3];
    const float* Wv       = (const float*)d_in[4];
    const float* gamma    = (const float*)d_in[5];
    const float* beta     = (const float*)d_in[6];
    float* out = (float*)d_out;
    char* ws = (char*)d_ws;

    u16* vcode_bf = (u16*)(ws + OFF_VCODEBF);
    u16* obs_bf   = (u16*)(ws + OFF_OBSBF);
    u16* wq_bf    = (u16*)(ws + OFF_WQ);
    u16* wk_bf    = (u16*)(ws + OFF_WK);
    u16* wv_bf    = (u16*)(ws + OFF_WV);
    u16* q_bf     = (u16*)(ws + OFF_QBF);
    u16* k_bf     = (u16*)(ws + OFF_KBF);
    float* vval   = (float*)(ws + OFF_VVAL);
    u16* obsk_bf  = (u16*)(ws + OFF_OBSK);
    u16* obsvT_bf = (u16*)(ws + OFF_OBSVT);
    float* S      = (float*)(ws + OFF_S);
    float* w0     = (float*)(ws + OFF_W0);
    float* selfS  = (float*)(ws + OFF_SELF);
    float* O      = (float*)(ws + OFF_O);

    // 1. casts
    cast_bf<<<N_ROWS * E_DIM / 4 / 256, 256, 0, stream>>>(v_code, vcode_bf, N_ROWS * E_DIM / 4);
    cast_bf<<<M_ROWS * E_DIM / 4 / 256, 256, 0, stream>>>(obs_code, obs_bf, M_ROWS * E_DIM / 4);
    cast_bf<<<E_DIM * E_DIM / 4 / 256, 256, 0, stream>>>(Wq, wq_bf, E_DIM * E_DIM / 4);
    cast_bf<<<E_DIM * E_DIM / 4 / 256, 256, 0, stream>>>(Wk, wk_bf, E_DIM * E_DIM / 4);
    cast_bf<<<E_DIM * E_DIM / 4 / 256, 256, 0, stream>>>(Wv, wv_bf, E_DIM * E_DIM / 4);

    // 2. projections (y = x @ W.T)
    dim3 gN(E_DIM / 64, N_ROWS / 64);   // (8,128)
    dim3 gM(E_DIM / 64, M_ROWS / 64);   // (8,64)
    gemm_bt<1><<<gN, 256, 0, stream>>>(vcode_bf, E_DIM, wq_bf, E_DIM, q_bf,   E_DIM, E_DIM);
    gemm_bt<1><<<gN, 256, 0, stream>>>(vcode_bf, E_DIM, wk_bf, E_DIM, k_bf,   E_DIM, E_DIM);
    gemm_bt<0><<<gN, 256, 0, stream>>>(vcode_bf, E_DIM, wv_bf, E_DIM, vval,   E_DIM, E_DIM);
    gemm_bt<1><<<gM, 256, 0, stream>>>(obs_bf,   E_DIM, wk_bf, E_DIM, obsk_bf, E_DIM, E_DIM);
    gemm_bt<2><<<gM, 256, 0, stream>>>(obs_bf,   E_DIM, wv_bf, E_DIM, obsvT_bf, M_ROWS, E_DIM);

    // 3. self score
    self_dot<<<N_ROWS / 4, 256, 0, stream>>>(q_bf, k_bf, selfS);

    // 4. cross scores S = Q @ K_obs^T   [8192 x 4096]
    dim3 gS(M_ROWS / 64, N_ROWS / 64);  // (64,128)
    gemm_bt<0><<<gS, 256, 0, stream>>>(q_bf, E_DIM, obsk_bf, E_DIM, S, M_ROWS, E_DIM);

    // 5. softmax -> bf16 weights in place (row stride 2*M in u16), w0 separate
    softmax_row<<<N_ROWS, 256, 0, stream>>>(S, selfS, w0);

    // 6. O = W @ V_obs   (A = bf16 weights with lda = 2*M u16 elems, B = V^T)
    dim3 gO(E_DIM / 64, N_ROWS / 64);   // (8,128)
    gemm_bt<0><<<gO, 256, 0, stream>>>((const u16*)S, 2 * M_ROWS, obsvT_bf, M_ROWS, O, E_DIM, M_ROWS);

    // 7. residual + LayerNorm
    final_ln<<<N_ROWS, 256, 0, stream>>>(O, vval, w0, v_code, gamma, beta, out);
}

// Round 2
// 331.701 us; speedup vs baseline: 1.1866x; 1.1866x over previous
//
#include <hip/hip_runtime.h>
#include <hip/hip_bf16.h>

typedef unsigned short u16;
typedef __bf16 bf16x8 __attribute__((ext_vector_type(8)));
typedef float f32x4 __attribute__((ext_vector_type(4)));

#define N_ROWS 8192
#define M_ROWS 4096
#define E_DIM  512

// ---------- helpers ----------
__device__ __forceinline__ u16 f2bf(float f) {
    unsigned u = __float_as_uint(f);
    u += 0x7FFF + ((u >> 16) & 1);   // RNE
    return (u16)(u >> 16);
}
__device__ __forceinline__ float bf2f(u16 u) {
    return __uint_as_float(((unsigned)u) << 16);
}

#define GLD16(gp, lp) \
    __builtin_amdgcn_global_load_lds((const __attribute__((address_space(1))) void*)(gp), \
                                     (__attribute__((address_space(3))) void*)(lp), 16, 0, 0)

// ---------- cast fp32 -> bf16, 4 elems/thread ----------
__global__ __launch_bounds__(256)
void cast_bf(const float* __restrict__ in, u16* __restrict__ out, int n4) {
    int i = blockIdx.x * 256 + threadIdx.x;
    if (i < n4) {
        float4 f = reinterpret_cast<const float4*>(in)[i];
        ushort4 o;
        o.x = f2bf(f.x); o.y = f2bf(f.y); o.z = f2bf(f.z); o.w = f2bf(f.w);
        reinterpret_cast<ushort4*>(out)[i] = o;
    }
}

// ---------- 128x128 MFMA GEMM body (m97 structure) ----------
// C[i][j] = sum_k A[i][k]*B[j][k]; A,B bf16 K-contiguous.
// mode: 0 = fp32 row-major, 1 = bf16 row-major, 2 = bf16 transposed (C[col*ldc+row])
__device__ __forceinline__
void gemm128_body(const u16* __restrict__ A, int lda,
                  const u16* __restrict__ B, int ldb,
                  void* __restrict__ C, int ldc, int K,
                  int row0, int col0, int mode) {
    __shared__ u16 sA[128 * 32];   // row-major, unpadded (global_load_lds layout constraint)
    __shared__ u16 sB[128 * 32];

    const int tid  = threadIdx.x;
    const int wave = tid >> 6, lane = tid & 63;
    const int quad = lane >> 4, m16 = lane & 15;
    const int wr = (wave & 1) * 64;       // wave's 64-row quadrant
    const int wc = (wave >> 1) * 64;      // wave's 64-col quadrant

    // staging: wave w stages 16-row chunks {w, w+4} of each tile; lane -> (row=L/4, k=(L%4)*8)
    const int srow  = lane >> 2;
    const int skoff = (lane & 3) * 8;
    const u16* ag0 = A + (size_t)(row0 + wave * 16 + srow) * lda + skoff;
    const u16* ag1 = ag0 + (size_t)64 * lda;
    const u16* bg0 = B + (size_t)(col0 + wave * 16 + srow) * ldb + skoff;
    const u16* bg1 = bg0 + (size_t)64 * ldb;
    u16* la0 = &sA[(wave * 16) * 32];
    u16* la1 = &sA[(wave * 16 + 64) * 32];
    u16* lb0 = &sB[(wave * 16) * 32];
    u16* lb1 = &sB[(wave * 16 + 64) * 32];

    f32x4 acc[4][4];
#pragma unroll
    for (int i = 0; i < 4; ++i)
#pragma unroll
        for (int j = 0; j < 4; ++j) acc[i][j] = (f32x4){0.f, 0.f, 0.f, 0.f};

    for (int k0 = 0; k0 < K; k0 += 32) {
        GLD16(ag0 + k0, la0);
        GLD16(ag1 + k0, la1);
        GLD16(bg0 + k0, lb0);
        GLD16(bg1 + k0, lb1);
        __syncthreads();   // drains vmcnt (data arrival) + all waves ready

        bf16x8 a[4], b[4];
#pragma unroll
        for (int i = 0; i < 4; ++i)
            a[i] = *reinterpret_cast<const bf16x8*>(&sA[(wr + i * 16 + m16) * 32 + quad * 8]);
#pragma unroll
        for (int j = 0; j < 4; ++j)
            b[j] = *reinterpret_cast<const bf16x8*>(&sB[(wc + j * 16 + m16) * 32 + quad * 8]);
#pragma unroll
        for (int i = 0; i < 4; ++i)
#pragma unroll
            for (int j = 0; j < 4; ++j)
                acc[i][j] = __builtin_amdgcn_mfma_f32_16x16x32_bf16(a[i], b[j], acc[i][j], 0, 0, 0);
        __syncthreads();   // protect LDS before next iteration's staging
    }

    // epilogue: C/D layout col=lane&15, row=quad*4+r (HW-verified)
#pragma unroll
    for (int i = 0; i < 4; ++i) {
        const int rbase = row0 + wr + i * 16 + quad * 4;
#pragma unroll
        for (int j = 0; j < 4; ++j) {
            const int c = col0 + wc + j * 16 + m16;
#pragma unroll
            for (int r = 0; r < 4; ++r) {
                const float v = acc[i][j][r];
                const int rr = rbase + r;
                if (mode == 0) {
                    reinterpret_cast<float*>(C)[(size_t)rr * ldc + c] = v;
                } else if (mode == 1) {
                    reinterpret_cast<u16*>(C)[(size_t)rr * ldc + c] = f2bf(v);
                } else {
                    reinterpret_cast<u16*>(C)[(size_t)c * ldc + rr] = f2bf(v);
                }
            }
        }
    }
}

// ---------- batched projection GEMMs (grid.z picks descriptor) ----------
struct ProjArgs {
    const u16* A[5];
    const u16* B[5];
    void*      C[5];
    int        rows[5];
    int        mode[5];
    int        ldc[5];
};

__global__ __launch_bounds__(256)
void proj_gemm(ProjArgs p) {
    const int z = blockIdx.z;
    const int row0 = blockIdx.y * 128;
    if (row0 >= p.rows[z]) return;
    gemm128_body(p.A[z], E_DIM, p.B[z], E_DIM, p.C[z], p.ldc[z], E_DIM,
                 row0, blockIdx.x * 128, p.mode[z]);
}

// ---------- main GEMM (score / PV with optional split-K over grid.z) ----------
__global__ __launch_bounds__(256)
void gemm_main(const u16* __restrict__ A, int lda,
               const u16* __restrict__ B, int ldb,
               void* __restrict__ C, int ldc, int Kslice,
               long long cstride_bytes, int mode) {
    const int z = blockIdx.z;
    const u16* Az = A + (long long)z * Kslice;
    const u16* Bz = B + (long long)z * Kslice;
    void* Cz = (char*)C + (long long)z * cstride_bytes;
    gemm128_body(Az, lda, Bz, ldb, Cz, ldc, Kslice,
                 blockIdx.y * 128, blockIdx.x * 128, mode);
}

// ---------- self attention score: dot(q[n], k[n]) ----------
__global__ __launch_bounds__(256)
void self_dot(const u16* __restrict__ q, const u16* __restrict__ k,
              float* __restrict__ selfS) {
    const int wave = threadIdx.x >> 6, lane = threadIdx.x & 63;
    const int row = blockIdx.x * 4 + wave;
    const uint4 qa = *reinterpret_cast<const uint4*>(q + (size_t)row * E_DIM + lane * 8);
    const uint4 ka = *reinterpret_cast<const uint4*>(k + (size_t)row * E_DIM + lane * 8);
    unsigned qu[4] = {qa.x, qa.y, qa.z, qa.w};
    unsigned ku[4] = {ka.x, ka.y, ka.z, ka.w};
    float s = 0.f;
#pragma unroll
    for (int i = 0; i < 4; ++i) {
        s += bf2f((u16)(qu[i] & 0xFFFF)) * bf2f((u16)(ku[i] & 0xFFFF));
        s += bf2f((u16)(qu[i] >> 16))    * bf2f((u16)(ku[i] >> 16));
    }
#pragma unroll
    for (int off = 32; off; off >>= 1) s += __shfl_down(s, off);
    if (lane == 0) selfS[row] = s;
}

// ---------- row softmax over bf16 scores [self, row]; bf16 weights in place ----------
__global__ __launch_bounds__(256)
void softmax_row_bf(u16* __restrict__ S, const float* __restrict__ selfS,
                    float* __restrict__ w0) {
    __shared__ float lds[8];
    const int n = blockIdx.x, t = threadIdx.x;
    const int lane = t & 63, wave = t >> 6;
    u16* row = S + (size_t)n * M_ROWS;

    uint4 raw[2];
    raw[0] = reinterpret_cast<const uint4*>(row)[t];
    raw[1] = reinterpret_cast<const uint4*>(row)[t + 256];
    float v[16];
#pragma unroll
    for (int h = 0; h < 2; ++h) {
        unsigned u0 = raw[h].x, u1 = raw[h].y, u2 = raw[h].z, u3 = raw[h].w;
        v[h * 8 + 0] = bf2f((u16)(u0 & 0xFFFF)); v[h * 8 + 1] = bf2f((u16)(u0 >> 16));
        v[h * 8 + 2] = bf2f((u16)(u1 & 0xFFFF)); v[h * 8 + 3] = bf2f((u16)(u1 >> 16));
        v[h * 8 + 4] = bf2f((u16)(u2 & 0xFFFF)); v[h * 8 + 5] = bf2f((u16)(u2 >> 16));
        v[h * 8 + 6] = bf2f((u16)(u3 & 0xFFFF)); v[h * 8 + 7] = bf2f((u16)(u3 >> 16));
    }
    const float s0 = selfS[n];

    float lmax = s0;
#pragma unroll
    for (int i = 0; i < 16; ++i) lmax = fmaxf(lmax, v[i]);
#pragma unroll
    for (int off = 32; off; off >>= 1) lmax = fmaxf(lmax, __shfl_down(lmax, off));
    if (lane == 0) lds[wave] = lmax;
    __syncthreads();
    const float gmax = fmaxf(fmaxf(lds[0], lds[1]), fmaxf(lds[2], lds[3]));
    __syncthreads();

    const float invT = (float)(1.0 / 22.627416997969522);
    float lsum = 0.f;
#pragma unroll
    for (int i = 0; i < 16; ++i) { v[i] = expf((v[i] - gmax) * invT); lsum += v[i]; }
#pragma unroll
    for (int off = 32; off; off >>= 1) lsum += __shfl_down(lsum, off);
    if (lane == 0) lds[wave] = lsum;
    __syncthreads();
    const float p0 = expf((s0 - gmax) * invT);
    const float gsum = lds[0] + lds[1] + lds[2] + lds[3] + p0;
    const float inv = 1.f / gsum;

#pragma unroll
    for (int h = 0; h < 2; ++h) {
        unsigned o0 = (unsigned)f2bf(v[h*8+0] * inv) | ((unsigned)f2bf(v[h*8+1] * inv) << 16);
        unsigned o1 = (unsigned)f2bf(v[h*8+2] * inv) | ((unsigned)f2bf(v[h*8+3] * inv) << 16);
        unsigned o2 = (unsigned)f2bf(v[h*8+4] * inv) | ((unsigned)f2bf(v[h*8+5] * inv) << 16);
        unsigned o3 = (unsigned)f2bf(v[h*8+6] * inv) | ((unsigned)f2bf(v[h*8+7] * inv) << 16);
        reinterpret_cast<uint4*>(row)[h == 0 ? t : t + 256] = (uint4){o0, o1, o2, o3};
    }
    if (t == 0) w0[n] = p0 * inv;
}

// ---------- epilogue: LN(w0*v_value + sum_z O_z + v_code) ----------
__global__ __launch_bounds__(256)
void final_ln(const u16* __restrict__ O /* 4 bf16 slices */,
              const float* __restrict__ vval,
              const float* __restrict__ w0, const float* __restrict__ vcode,
              const float* __restrict__ gamma, const float* __restrict__ beta,
              float* __restrict__ out) {
    __shared__ float lds[8];
    const int n = blockIdx.x, t = threadIdx.x;
    const int lane = t & 63, wave = t >> 6;
    const size_t base = (size_t)n * E_DIM;
    const size_t NE = (size_t)N_ROWS * E_DIM;
    const float a = w0[n];

    float o0 = 0.f, o1 = 0.f;
#pragma unroll
    for (int z = 0; z < 4; ++z) {
        o0 += bf2f(O[z * NE + base + t]);
        o1 += bf2f(O[z * NE + base + t + 256]);
    }
    float x0 = fmaf(a, vval[base + t],       o0) + vcode[base + t];
    float x1 = fmaf(a, vval[base + t + 256], o1) + vcode[base + t + 256];

    float s = x0 + x1;
#pragma unroll
    for (int off = 32; off; off >>= 1) s += __shfl_down(s, off);
    if (lane == 0) lds[wave] = s;
    __syncthreads();
    const float mu = (lds[0] + lds[1] + lds[2] + lds[3]) * (1.0f / E_DIM);
    __syncthreads();

    const float d0 = x0 - mu, d1 = x1 - mu;
    float vs = d0 * d0 + d1 * d1;
#pragma unroll
    for (int off = 32; off; off >>= 1) vs += __shfl_down(vs, off);
    if (lane == 0) lds[wave] = vs;
    __syncthreads();
    const float var = (lds[0] + lds[1] + lds[2] + lds[3]) * (1.0f / E_DIM);
    const float rs = rsqrtf(var + 1e-6f);

    out[base + t]       = d0 * rs * gamma[t]       + beta[t];
    out[base + t + 256] = d1 * rs * gamma[t + 256] + beta[t + 256];
}

// ---------- workspace layout (bytes; total ~157.4 MiB, fits round-1's budget) ----------
#define OFF_VCODEBF 0ull
#define OFF_OBSBF   8388608ull
#define OFF_WQ      12582912ull
#define OFF_WK      13107200ull
#define OFF_WV      13631488ull
#define OFF_QBF     14680064ull
#define OFF_KBF     23068672ull
#define OFF_OBSK    31457280ull
#define OFF_OBSVT   35651584ull
#define OFF_VVAL    39845888ull
#define OFF_S       56623104ull
#define OFF_O       123731968ull
#define OFF_W0      157286400ull
#define OFF_SELF    157319168ull

extern "C" void kernel_launch(void* const* d_in, const int* in_sizes, int n_in,
                              void* d_out, int out_size, void* d_ws, size_t ws_size,
                              hipStream_t stream) {
    const float* v_code   = (const float*)d_in[0];
    const float* obs_code = (const float*)d_in[1];
    const float* Wq       = (const float*)d_in[2];
    const float* Wk       = (const float*)d_in[3];
    const float* Wv       = (const float*)d_in[4];
    const float* gamma    = (const float*)d_in[5];
    const float* beta     = (const float*)d_in[6];
    float* out = (float*)d_out;
    char* ws = (char*)d_ws;

    u16* vcode_bf = (u16*)(ws + OFF_VCODEBF);
    u16* obs_bf   = (u16*)(ws + OFF_OBSBF);
    u16* wq_bf    = (u16*)(ws + OFF_WQ);
    u16* wk_bf    = (u16*)(ws + OFF_WK);
    u16* wv_bf    = (u16*)(ws + OFF_WV);
    u16* q_bf     = (u16*)(ws + OFF_QBF);
    u16* k_bf     = (u16*)(ws + OFF_KBF);
    u16* obsk_bf  = (u16*)(ws + OFF_OBSK);
    u16* obsvT_bf = (u16*)(ws + OFF_OBSVT);
    float* vval   = (float*)(ws + OFF_VVAL);
    u16* S        = (u16*)(ws + OFF_S);
    u16* O        = (u16*)(ws + OFF_O);
    float* w0     = (float*)(ws + OFF_W0);
    float* selfS  = (float*)(ws + OFF_SELF);

    // 1. casts
    cast_bf<<<N_ROWS * E_DIM / 4 / 256, 256, 0, stream>>>(v_code, vcode_bf, N_ROWS * E_DIM / 4);
    cast_bf<<<M_ROWS * E_DIM / 4 / 256, 256, 0, stream>>>(obs_code, obs_bf, M_ROWS * E_DIM / 4);
    cast_bf<<<E_DIM * E_DIM / 4 / 256, 256, 0, stream>>>(Wq, wq_bf, E_DIM * E_DIM / 4);
    cast_bf<<<E_DIM * E_DIM / 4 / 256, 256, 0, stream>>>(Wk, wk_bf, E_DIM * E_DIM / 4);
    cast_bf<<<E_DIM * E_DIM / 4 / 256, 256, 0, stream>>>(Wv, wv_bf, E_DIM * E_DIM / 4);

    // 2. all five projections in one launch (grid.z = descriptor)
    ProjArgs p;
    p.A[0] = vcode_bf; p.B[0] = wq_bf; p.C[0] = q_bf;     p.rows[0] = N_ROWS; p.mode[0] = 1; p.ldc[0] = E_DIM;
    p.A[1] = vcode_bf; p.B[1] = wk_bf; p.C[1] = k_bf;     p.rows[1] = N_ROWS; p.mode[1] = 1; p.ldc[1] = E_DIM;
    p.A[2] = vcode_bf; p.B[2] = wv_bf; p.C[2] = vval;     p.rows[2] = N_ROWS; p.mode[2] = 0; p.ldc[2] = E_DIM;
    p.A[3] = obs_bf;   p.B[3] = wk_bf; p.C[3] = obsk_bf;  p.rows[3] = M_ROWS; p.mode[3] = 1; p.ldc[3] = E_DIM;
    p.A[4] = obs_bf;   p.B[4] = wv_bf; p.C[4] = obsvT_bf; p.rows[4] = M_ROWS; p.mode[4] = 2; p.ldc[4] = M_ROWS;
    proj_gemm<<<dim3(E_DIM / 128, N_ROWS / 128, 5), 256, 0, stream>>>(p);

    // 3. self score
    self_dot<<<N_ROWS / 4, 256, 0, stream>>>(q_bf, k_bf, selfS);

    // 4. cross scores S = Q @ K_obs^T  [8192 x 4096], bf16 out
    gemm_main<<<dim3(M_ROWS / 128, N_ROWS / 128, 1), 256, 0, stream>>>(
        q_bf, E_DIM, obsk_bf, E_DIM, S, M_ROWS, E_DIM, 0, 1);

    // 5. softmax -> bf16 weights in place
    softmax_row_bf<<<N_ROWS, 256, 0, stream>>>(S, selfS, w0);

    // 6. O_z = W[:, z*1024:(z+1)*1024] @ V_obs[z*1024:(z+1)*1024, :]  (split-K=4, bf16 slices)
    gemm_main<<<dim3(E_DIM / 128, N_ROWS / 128, 4), 256, 0, stream>>>(
        S, M_ROWS, obsvT_bf, M_ROWS, O, E_DIM, M_ROWS / 4,
        (long long)N_ROWS * E_DIM * 2, 1);

    // 7. residual + LayerNorm (sums the 4 PV slices)
    final_ln<<<N_ROWS, 256, 0, stream>>>(O, vval, w0, v_code, gamma, beta, out);
}

// Round 3
// 330.263 us; speedup vs baseline: 1.1918x; 1.0044x over previous
//
#include <hip/hip_runtime.h>
#include <hip/hip_bf16.h>

typedef unsigned short u16;
typedef __bf16 bf16x8 __attribute__((ext_vector_type(8)));
typedef float f32x4 __attribute__((ext_vector_type(4)));

#define N_ROWS 8192
#define M_ROWS 4096
#define E_DIM  512
#define KSPLIT 8

// ---------- helpers ----------
__device__ __forceinline__ u16 f2bf(float f) {
    unsigned u = __float_as_uint(f);
    u += 0x7FFF + ((u >> 16) & 1);   // RNE
    return (u16)(u >> 16);
}
__device__ __forceinline__ float bf2f(u16 u) {
    return __uint_as_float(((unsigned)u) << 16);
}

#define GLD16(gp, lp) \
    __builtin_amdgcn_global_load_lds((const __attribute__((address_space(1))) void*)(gp), \
                                     (__attribute__((address_space(3))) void*)(lp), 16, 0, 0)

// ---------- cast fp32 -> bf16, 4 elems/thread ----------
__global__ __launch_bounds__(256)
void cast_bf(const float* __restrict__ in, u16* __restrict__ out, int n4) {
    int i = blockIdx.x * 256 + threadIdx.x;
    if (i < n4) {
        float4 f = reinterpret_cast<const float4*>(in)[i];
        ushort4 o;
        o.x = f2bf(f.x); o.y = f2bf(f.y); o.z = f2bf(f.z); o.w = f2bf(f.w);
        reinterpret_cast<ushort4*>(out)[i] = o;
    }
}

// ---------- 128x128 MFMA GEMM body, single-barrier double-buffered pipeline ----------
// C[i][j] = sum_k A[i][k]*B[j][k]; A,B bf16 K-contiguous.
// mode: 0 = fp32 row-major, 1 = bf16 row-major, 2 = bf16 transposed (C[col*ldc+row])
__device__ __forceinline__
void gemm128_body(const u16* __restrict__ A, int lda,
                  const u16* __restrict__ B, int ldb,
                  void* __restrict__ C, int ldc, int K,
                  int row0, int col0, int mode) {
    __shared__ u16 sA[2][128 * 32];   // row-major, unpadded (global_load_lds layout constraint)
    __shared__ u16 sB[2][128 * 32];

    const int tid  = threadIdx.x;
    const int wave = tid >> 6, lane = tid & 63;
    const int quad = lane >> 4, m16 = lane & 15;
    const int wr = (wave & 1) * 64;       // wave's 64-row quadrant
    const int wc = (wave >> 1) * 64;      // wave's 64-col quadrant

    // staging: wave w stages 16-row chunks {w, w+4}; lane -> (row=L/4, k=(L%4)*8)
    const int srow  = lane >> 2;
    const int skoff = (lane & 3) * 8;
    const u16* ag0 = A + (size_t)(row0 + wave * 16 + srow) * lda + skoff;
    const u16* ag1 = ag0 + (size_t)64 * lda;
    const u16* bg0 = B + (size_t)(col0 + wave * 16 + srow) * ldb + skoff;
    const u16* bg1 = bg0 + (size_t)64 * ldb;
    const int lo0 = (wave * 16) * 32;
    const int lo1 = (wave * 16 + 64) * 32;

    f32x4 acc[4][4];
#pragma unroll
    for (int i = 0; i < 4; ++i)
#pragma unroll
        for (int j = 0; j < 4; ++j) acc[i][j] = (f32x4){0.f, 0.f, 0.f, 0.f};

    // prologue: stage k=0 into buffer 0
    GLD16(ag0, &sA[0][lo0]); GLD16(ag1, &sA[0][lo1]);
    GLD16(bg0, &sB[0][lo0]); GLD16(bg1, &sB[0][lo1]);

    int kb = 0;
    for (int k0 = 0; k0 < K; k0 += 32, kb ^= 1) {
        __syncthreads();   // drains vmcnt: buf[kb] data landed; lgkmcnt: prior reads of buf[kb^1] done
        // prefetch next tile into the other buffer while we compute (last iter: harmless reload of k=0)
        const int kn = (k0 + 32 < K) ? (k0 + 32) : 0;
        GLD16(ag0 + kn, &sA[kb ^ 1][lo0]); GLD16(ag1 + kn, &sA[kb ^ 1][lo1]);
        GLD16(bg0 + kn, &sB[kb ^ 1][lo0]); GLD16(bg1 + kn, &sB[kb ^ 1][lo1]);

        bf16x8 a[4], b[4];
#pragma unroll
        for (int i = 0; i < 4; ++i)
            a[i] = *reinterpret_cast<const bf16x8*>(&sA[kb][(wr + i * 16 + m16) * 32 + quad * 8]);
#pragma unroll
        for (int j = 0; j < 4; ++j)
            b[j] = *reinterpret_cast<const bf16x8*>(&sB[kb][(wc + j * 16 + m16) * 32 + quad * 8]);
#pragma unroll
        for (int i = 0; i < 4; ++i)
#pragma unroll
            for (int j = 0; j < 4; ++j)
                acc[i][j] = __builtin_amdgcn_mfma_f32_16x16x32_bf16(a[i], b[j], acc[i][j], 0, 0, 0);
    }

    // epilogue: C/D layout col=lane&15, row=quad*4+r (HW-verified)
#pragma unroll
    for (int i = 0; i < 4; ++i) {
        const int rbase = row0 + wr + i * 16 + quad * 4;
#pragma unroll
        for (int j = 0; j < 4; ++j) {
            const int c = col0 + wc + j * 16 + m16;
#pragma unroll
            for (int r = 0; r < 4; ++r) {
                const float v = acc[i][j][r];
                const int rr = rbase + r;
                if (mode == 0) {
                    reinterpret_cast<float*>(C)[(size_t)rr * ldc + c] = v;
                } else if (mode == 1) {
                    reinterpret_cast<u16*>(C)[(size_t)rr * ldc + c] = f2bf(v);
                } else {
                    reinterpret_cast<u16*>(C)[(size_t)c * ldc + rr] = f2bf(v);
                }
            }
        }
    }
}

// ---------- batched projection GEMMs (grid.z picks descriptor) ----------
struct ProjArgs {
    const u16* A[5];
    const u16* B[5];
    void*      C[5];
    int        rows[5];
    int        mode[5];
    int        ldc[5];
};

__global__ __launch_bounds__(256)
void proj_gemm(ProjArgs p) {
    const int z = blockIdx.z;
    const int row0 = blockIdx.y * 128;
    if (row0 >= p.rows[z]) return;
    gemm128_body(p.A[z], E_DIM, p.B[z], E_DIM, p.C[z], p.ldc[z], E_DIM,
                 row0, blockIdx.x * 128, p.mode[z]);
}

// ---------- main GEMM (score / PV with optional split-K over grid.z) ----------
__global__ __launch_bounds__(256)
void gemm_main(const u16* __restrict__ A, int lda,
               const u16* __restrict__ B, int ldb,
               void* __restrict__ C, int ldc, int Kslice,
               long long cstride_bytes, int mode) {
    const int z = blockIdx.z;
    const u16* Az = A + (long long)z * Kslice;
    const u16* Bz = B + (long long)z * Kslice;
    void* Cz = (char*)C + (long long)z * cstride_bytes;
    gemm128_body(Az, lda, Bz, ldb, Cz, ldc, Kslice,
                 blockIdx.y * 128, blockIdx.x * 128, mode);
}

// ---------- self attention score: dot(q[n], k[n]) ----------
__global__ __launch_bounds__(256)
void self_dot(const u16* __restrict__ q, const u16* __restrict__ k,
              float* __restrict__ selfS) {
    const int wave = threadIdx.x >> 6, lane = threadIdx.x & 63;
    const int row = blockIdx.x * 4 + wave;
    const uint4 qa = *reinterpret_cast<const uint4*>(q + (size_t)row * E_DIM + lane * 8);
    const uint4 ka = *reinterpret_cast<const uint4*>(k + (size_t)row * E_DIM + lane * 8);
    unsigned qu[4] = {qa.x, qa.y, qa.z, qa.w};
    unsigned ku[4] = {ka.x, ka.y, ka.z, ka.w};
    float s = 0.f;
#pragma unroll
    for (int i = 0; i < 4; ++i) {
        s += bf2f((u16)(qu[i] & 0xFFFF)) * bf2f((u16)(ku[i] & 0xFFFF));
        s += bf2f((u16)(qu[i] >> 16))    * bf2f((u16)(ku[i] >> 16));
    }
#pragma unroll
    for (int off = 32; off; off >>= 1) s += __shfl_down(s, off);
    if (lane == 0) selfS[row] = s;
}

// ---------- row softmax over bf16 scores [self, row]; bf16 weights in place ----------
__global__ __launch_bounds__(256)
void softmax_row_bf(u16* __restrict__ S, const float* __restrict__ selfS,
                    float* __restrict__ w0) {
    __shared__ float lds[8];
    const int n = blockIdx.x, t = threadIdx.x;
    const int lane = t & 63, wave = t >> 6;
    u16* row = S + (size_t)n * M_ROWS;

    uint4 raw[2];
    raw[0] = reinterpret_cast<const uint4*>(row)[t];
    raw[1] = reinterpret_cast<const uint4*>(row)[t + 256];
    float v[16];
#pragma unroll
    for (int h = 0; h < 2; ++h) {
        unsigned u0 = raw[h].x, u1 = raw[h].y, u2 = raw[h].z, u3 = raw[h].w;
        v[h * 8 + 0] = bf2f((u16)(u0 & 0xFFFF)); v[h * 8 + 1] = bf2f((u16)(u0 >> 16));
        v[h * 8 + 2] = bf2f((u16)(u1 & 0xFFFF)); v[h * 8 + 3] = bf2f((u16)(u1 >> 16));
        v[h * 8 + 4] = bf2f((u16)(u2 & 0xFFFF)); v[h * 8 + 5] = bf2f((u16)(u2 >> 16));
        v[h * 8 + 6] = bf2f((u16)(u3 & 0xFFFF)); v[h * 8 + 7] = bf2f((u16)(u3 >> 16));
    }
    const float s0 = selfS[n];

    float lmax = s0;
#pragma unroll
    for (int i = 0; i < 16; ++i) lmax = fmaxf(lmax, v[i]);
#pragma unroll
    for (int off = 32; off; off >>= 1) lmax = fmaxf(lmax, __shfl_down(lmax, off));
    if (lane == 0) lds[wave] = lmax;
    __syncthreads();
    const float gmax = fmaxf(fmaxf(lds[0], lds[1]), fmaxf(lds[2], lds[3]));
    __syncthreads();

    const float invT = (float)(1.0 / 22.627416997969522);
    float lsum = 0.f;
#pragma unroll
    for (int i = 0; i < 16; ++i) { v[i] = expf((v[i] - gmax) * invT); lsum += v[i]; }
#pragma unroll
    for (int off = 32; off; off >>= 1) lsum += __shfl_down(lsum, off);
    if (lane == 0) lds[wave] = lsum;
    __syncthreads();
    const float p0 = expf((s0 - gmax) * invT);
    const float gsum = lds[0] + lds[1] + lds[2] + lds[3] + p0;
    const float inv = 1.f / gsum;

#pragma unroll
    for (int h = 0; h < 2; ++h) {
        unsigned o0 = (unsigned)f2bf(v[h*8+0] * inv) | ((unsigned)f2bf(v[h*8+1] * inv) << 16);
        unsigned o1 = (unsigned)f2bf(v[h*8+2] * inv) | ((unsigned)f2bf(v[h*8+3] * inv) << 16);
        unsigned o2 = (unsigned)f2bf(v[h*8+4] * inv) | ((unsigned)f2bf(v[h*8+5] * inv) << 16);
        unsigned o3 = (unsigned)f2bf(v[h*8+6] * inv) | ((unsigned)f2bf(v[h*8+7] * inv) << 16);
        reinterpret_cast<uint4*>(row)[h == 0 ? t : t + 256] = (uint4){o0, o1, o2, o3};
    }
    if (t == 0) w0[n] = p0 * inv;
}

// ---------- epilogue: LN(w0*v_value + sum_z O_z + v_code) ----------
__global__ __launch_bounds__(256)
void final_ln(const u16* __restrict__ O /* KSPLIT bf16 slices */,
              const float* __restrict__ vval,
              const float* __restrict__ w0, const float* __restrict__ vcode,
              const float* __restrict__ gamma, const float* __restrict__ beta,
              float* __restrict__ out) {
    __shared__ float lds[8];
    const int n = blockIdx.x, t = threadIdx.x;
    const int lane = t & 63, wave = t >> 6;
    const size_t base = (size_t)n * E_DIM;
    const size_t NE = (size_t)N_ROWS * E_DIM;
    const float a = w0[n];

    float o0 = 0.f, o1 = 0.f;
#pragma unroll
    for (int z = 0; z < KSPLIT; ++z) {
        o0 += bf2f(O[z * NE + base + t]);
        o1 += bf2f(O[z * NE + base + t + 256]);
    }
    float x0 = fmaf(a, vval[base + t],       o0) + vcode[base + t];
    float x1 = fmaf(a, vval[base + t + 256], o1) + vcode[base + t + 256];

    float s = x0 + x1;
#pragma unroll
    for (int off = 32; off; off >>= 1) s += __shfl_down(s, off);
    if (lane == 0) lds[wave] = s;
    __syncthreads();
    const float mu = (lds[0] + lds[1] + lds[2] + lds[3]) * (1.0f / E_DIM);
    __syncthreads();

    const float d0 = x0 - mu, d1 = x1 - mu;
    float vs = d0 * d0 + d1 * d1;
#pragma unroll
    for (int off = 32; off; off >>= 1) vs += __shfl_down(vs, off);
    if (lane == 0) lds[wave] = vs;
    __syncthreads();
    const float var = (lds[0] + lds[1] + lds[2] + lds[3]) * (1.0f / E_DIM);
    const float rs = rsqrtf(var + 1e-6f);

    out[base + t]       = d0 * rs * gamma[t]       + beta[t];
    out[base + t + 256] = d1 * rs * gamma[t + 256] + beta[t + 256];
}

// ---------- workspace layout (bytes; total 190,382,080 = R0's proven footprint) ----------
#define OFF_VCODEBF 0ull
#define OFF_OBSBF   8388608ull
#define OFF_WQ      12582912ull
#define OFF_WK      13107200ull
#define OFF_WV      13631488ull
#define OFF_QBF     14155776ull
#define OFF_KBF     22544384ull
#define OFF_OBSK    30932992ull
#define OFF_OBSVT   35127296ull
#define OFF_VVAL    39321600ull
#define OFF_S       56098816ull
#define OFF_O       123207680ull
#define OFF_W0      190316544ull
#define OFF_SELF    190349312ull

extern "C" void kernel_launch(void* const* d_in, const int* in_sizes, int n_in,
                              void* d_out, int out_size, void* d_ws, size_t ws_size,
                              hipStream_t stream) {
    const float* v_code   = (const float*)d_in[0];
    const float* obs_code = (const float*)d_in[1];
    const float* Wq       = (const float*)d_in[2];
    const float* Wk       = (const float*)d_in[3];
    const float* Wv       = (const float*)d_in[4];
    const float* gamma    = (const float*)d_in[5];
    const float* beta     = (const float*)d_in[6];
    float* out = (float*)d_out;
    char* ws = (char*)d_ws;

    u16* vcode_bf = (u16*)(ws + OFF_VCODEBF);
    u16* obs_bf   = (u16*)(ws + OFF_OBSBF);
    u16* wq_bf    = (u16*)(ws + OFF_WQ);
    u16* wk_bf    = (u16*)(ws + OFF_WK);
    u16* wv_bf    = (u16*)(ws + OFF_WV);
    u16* q_bf     = (u16*)(ws + OFF_QBF);
    u16* k_bf     = (u16*)(ws + OFF_KBF);
    u16* obsk_bf  = (u16*)(ws + OFF_OBSK);
    u16* obsvT_bf = (u16*)(ws + OFF_OBSVT);
    float* vval   = (float*)(ws + OFF_VVAL);
    u16* S        = (u16*)(ws + OFF_S);
    u16* O        = (u16*)(ws + OFF_O);
    float* w0     = (float*)(ws + OFF_W0);
    float* selfS  = (float*)(ws + OFF_SELF);

    // 1. casts
    cast_bf<<<N_ROWS * E_DIM / 4 / 256, 256, 0, stream>>>(v_code, vcode_bf, N_ROWS * E_DIM / 4);
    cast_bf<<<M_ROWS * E_DIM / 4 / 256, 256, 0, stream>>>(obs_code, obs_bf, M_ROWS * E_DIM / 4);
    cast_bf<<<E_DIM * E_DIM / 4 / 256, 256, 0, stream>>>(Wq, wq_bf, E_DIM * E_DIM / 4);
    cast_bf<<<E_DIM * E_DIM / 4 / 256, 256, 0, stream>>>(Wk, wk_bf, E_DIM * E_DIM / 4);
    cast_bf<<<E_DIM * E_DIM / 4 / 256, 256, 0, stream>>>(Wv, wv_bf, E_DIM * E_DIM / 4);

    // 2. all five projections in one launch (grid.z = descriptor)
    ProjArgs p;
    p.A[0] = vcode_bf; p.B[0] = wq_bf; p.C[0] = q_bf;     p.rows[0] = N_ROWS; p.mode[0] = 1; p.ldc[0] = E_DIM;
    p.A[1] = vcode_bf; p.B[1] = wk_bf; p.C[1] = k_bf;     p.rows[1] = N_ROWS; p.mode[1] = 1; p.ldc[1] = E_DIM;
    p.A[2] = vcode_bf; p.B[2] = wv_bf; p.C[2] = vval;     p.rows[2] = N_ROWS; p.mode[2] = 0; p.ldc[2] = E_DIM;
    p.A[3] = obs_bf;   p.B[3] = wk_bf; p.C[3] = obsk_bf;  p.rows[3] = M_ROWS; p.mode[3] = 1; p.ldc[3] = E_DIM;
    p.A[4] = obs_bf;   p.B[4] = wv_bf; p.C[4] = obsvT_bf; p.rows[4] = M_ROWS; p.mode[4] = 2; p.ldc[4] = M_ROWS;
    proj_gemm<<<dim3(E_DIM / 128, N_ROWS / 128, 5), 256, 0, stream>>>(p);

    // 3. self score
    self_dot<<<N_ROWS / 4, 256, 0, stream>>>(q_bf, k_bf, selfS);

    // 4. cross scores S = Q @ K_obs^T  [8192 x 4096], bf16 out
    gemm_main<<<dim3(M_ROWS / 128, N_ROWS / 128, 1), 256, 0, stream>>>(
        q_bf, E_DIM, obsk_bf, E_DIM, S, M_ROWS, E_DIM, 0, 1);

    // 5. softmax -> bf16 weights in place
    softmax_row_bf<<<N_ROWS, 256, 0, stream>>>(S, selfS, w0);

    // 6. O_z = W[:, z*512:(z+1)*512] @ V_obs[z*512:(z+1)*512, :]  (split-K=8, bf16 slices)
    gemm_main<<<dim3(E_DIM / 128, N_ROWS / 128, KSPLIT), 256, 0, stream>>>(
        S, M_ROWS, obsvT_bf, M_ROWS, O, E_DIM, M_ROWS / KSPLIT,
        (long long)N_ROWS * E_DIM * 2, 1);

    // 7. residual + LayerNorm (sums the KSPLIT PV slices)
    final_ln<<<N_ROWS, 256, 0, stream>>>(O, vval, w0, v_code, gamma, beta, out);
}